// Round 2
// baseline (945.805 us; speedup 1.0000x reference)
//
#include <hip/hip_runtime.h>
#include <hip/hip_bf16.h>
#include <math.h>

#define EPSQ 1e-5f

typedef __attribute__((ext_vector_type(4))) float f32x4;
typedef __attribute__((ext_vector_type(8))) short bf16x8;
typedef __attribute__((ext_vector_type(4))) unsigned short us4;

// round-to-nearest-even f32 -> bf16 bit pattern (exact for our small integers)
__device__ __forceinline__ unsigned short f2bf(float f) {
  union { float f; unsigned int u; } v; v.f = f;
  unsigned int u = v.u;
  return (unsigned short)((u + 0x7fffu + ((u >> 16) & 1u)) >> 16);
}

__device__ __forceinline__ void gload_lds16(const void* g, void* l) {
  __builtin_amdgcn_global_load_lds(
      (__attribute__((address_space(1))) void*)g,
      (__attribute__((address_space(3))) void*)l, 16, 0, 0);
}

// ---------------- weight |w| sum (double, deterministic to ~1e-15) ----------------
__global__ void wabs_kernel(const float* __restrict__ w, int n4, double* __restrict__ sum) {
  __shared__ double sm[256];
  const float4* w4 = (const float4*)w;
  double acc = 0.0;
  const int stride = gridDim.x * blockDim.x;
  for (int i = blockIdx.x * blockDim.x + threadIdx.x; i < n4; i += stride) {
    float4 v = w4[i];
    acc += (double)fabsf(v.x) + (double)fabsf(v.y) + (double)fabsf(v.z) + (double)fabsf(v.w);
  }
  sm[threadIdx.x] = acc;
  __syncthreads();
  for (int s = 128; s > 0; s >>= 1) {
    if ((int)threadIdx.x < s) sm[threadIdx.x] += sm[threadIdx.x + s];
    __syncthreads();
  }
  if (threadIdx.x == 0) atomicAdd(sum, sm[0]);
}

// ---------------- ternary weight quant -> bf16 {-1,0,1} ----------------
__global__ void wquant_kernel(const float* __restrict__ w, int n4,
                              const double* __restrict__ sum, double inv_n,
                              unsigned short* __restrict__ wq) {
  const float s = (float)fmax(*sum * inv_n, (double)EPSQ);
  const float scale = 1.0f / s;  // same fp32 division as the reference
  const int i = blockIdx.x * blockDim.x + threadIdx.x;
  if (i >= n4) return;
  float4 v = ((const float4*)w)[i];
  us4 o;
  o.x = f2bf(fminf(1.f, fmaxf(-1.f, rintf(v.x * scale))));
  o.y = f2bf(fminf(1.f, fmaxf(-1.f, rintf(v.y * scale))));
  o.z = f2bf(fminf(1.f, fmaxf(-1.f, rintf(v.z * scale))));
  o.w = f2bf(fminf(1.f, fmaxf(-1.f, rintf(v.w * scale))));
  ((us4*)wq)[i] = o;
}

// ---------------- per-token absmax int8 quant -> bf16 ints, one block/row ----------------
__global__ void aquant_kernel(const float* __restrict__ x, int K,
                              unsigned short* __restrict__ q, float* __restrict__ arow) {
  const int row = blockIdx.x;
  const int n4 = K >> 2;
  const float4* xr = (const float4*)(x + (size_t)row * K);
  float m = 0.f;
  for (int c = threadIdx.x; c < n4; c += blockDim.x) {
    float4 v = xr[c];
    m = fmaxf(m, fmaxf(fmaxf(fabsf(v.x), fabsf(v.y)), fmaxf(fabsf(v.z), fabsf(v.w))));
  }
  __shared__ float sm[256];
  sm[threadIdx.x] = m;
  __syncthreads();
  for (int s = 128; s > 0; s >>= 1) {
    if ((int)threadIdx.x < s) sm[threadIdx.x] = fmaxf(sm[threadIdx.x], sm[threadIdx.x + s]);
    __syncthreads();
  }
  const float mv = fmaxf(sm[0], EPSQ);
  const float scale = 127.0f / mv;   // same fp32 division as the reference
  if (threadIdx.x == 0) arow[row] = mv * (1.0f / 127.0f);
  us4* qr = (us4*)(q + (size_t)row * K);
  for (int c = threadIdx.x; c < n4; c += blockDim.x) {
    float4 v = xr[c];
    us4 o;
    o.x = f2bf(fminf(127.f, fmaxf(-128.f, rintf(v.x * scale))));
    o.y = f2bf(fminf(127.f, fmaxf(-128.f, rintf(v.y * scale))));
    o.z = f2bf(fminf(127.f, fmaxf(-128.f, rintf(v.z * scale))));
    o.w = f2bf(fminf(127.f, fmaxf(-128.f, rintf(v.w * scale))));
    qr[c] = o;
  }
}

// ---------------- fused gate/up GEMM: H = silu(Q*W1^T * s) * (Q*W2^T * s) ----------------
#define BM 128
#define BN 128
#define BK 32

__launch_bounds__(256, 2)
__global__ void gemm_gateup(const unsigned short* __restrict__ Aq,   // [Mc][K] bf16 ints
                            const unsigned short* __restrict__ W1q,  // [N][K] bf16 ternary
                            const unsigned short* __restrict__ W2q,  // [N][K]
                            const float* __restrict__ arow,          // [Mc] dequant = rowmax/127
                            const double* __restrict__ wsum,
                            float* __restrict__ Hbuf,                // [Mc][N] fp32
                            const int N, const int K) {
  __shared__ __align__(16) unsigned short lA[BM * BK];
  __shared__ __align__(16) unsigned short lB1[BN * BK];
  __shared__ __align__(16) unsigned short lB2[BN * BK];

  const int tid = threadIdx.x;
  const int lane = tid & 63;
  const int wid = tid >> 6;           // 4 waves: 2x2 over 128x128, each 64x64
  const int wm = wid >> 1, wn = wid & 1;
  const int m0 = blockIdx.y * BM;
  const int n0 = blockIdx.x * BN;

  const double inv_n = 1.0 / 11534336.0;
  const float sw1 = (float)fmax(wsum[0] * inv_n, (double)EPSQ);
  const float sw2 = (float)fmax(wsum[1] * inv_n, (double)EPSQ);

  f32x4 acc1[4][4] = {};
  f32x4 acc2[4][4] = {};

  const size_t Kb = (size_t)K * 2;
  const int so = wid * 2048;          // this wave's 2KB slice per 8KB tile
  const char* Ab  = (const char*)Aq  + (size_t)m0 * Kb;
  const char* B1b = (const char*)W1q + (size_t)n0 * Kb;
  const char* B2b = (const char*)W2q + (size_t)n0 * Kb;

  for (int k0 = 0; k0 < K; k0 += BK) {
#pragma unroll
    for (int t = 0; t < 2; ++t) {
      const int o = so + t * 1024 + lane * 16;   // linear byte offset in [128][64B] tile
      const int r = o >> 6;
      const int cb = o & 63;
      const size_t goff = (size_t)r * Kb + (size_t)k0 * 2 + (size_t)cb;
      // LDS dest is wave-uniform; HW adds lane*16
      gload_lds16(Ab  + goff, (char*)lA  + so + t * 1024);
      gload_lds16(B1b + goff, (char*)lB1 + so + t * 1024);
      gload_lds16(B2b + goff, (char*)lB2 + so + t * 1024);
    }
    __syncthreads();

    const unsigned short* pa  = lA  + (wm * 64 + (lane & 15)) * BK + (lane >> 4) * 8;
    const unsigned short* pb1 = lB1 + (wn * 64 + (lane & 15)) * BK + (lane >> 4) * 8;
    const unsigned short* pb2 = lB2 + (wn * 64 + (lane & 15)) * BK + (lane >> 4) * 8;
    bf16x8 af[4];
#pragma unroll
    for (int i = 0; i < 4; ++i) af[i] = *(const bf16x8*)(pa + i * 16 * BK);
#pragma unroll
    for (int j = 0; j < 4; ++j) {
      bf16x8 b1 = *(const bf16x8*)(pb1 + j * 16 * BK);
      bf16x8 b2 = *(const bf16x8*)(pb2 + j * 16 * BK);
#pragma unroll
      for (int i = 0; i < 4; ++i) {
        acc1[i][j] = __builtin_amdgcn_mfma_f32_16x16x32_bf16(af[i], b1, acc1[i][j], 0, 0, 0);
        acc2[i][j] = __builtin_amdgcn_mfma_f32_16x16x32_bf16(af[i], b2, acc2[i][j], 0, 0, 0);
      }
    }
    __syncthreads();
  }

  // epilogue: dequant + silu(gate)*up, write fp32 H
#pragma unroll
  for (int i = 0; i < 4; ++i) {
    const int rb = m0 + wm * 64 + i * 16 + (lane >> 4) * 4;
#pragma unroll
    for (int qe = 0; qe < 4; ++qe) {
      const int grow = rb + qe;
      const float a = arow[grow];
      const float f1 = a * sw1;
      const float f2 = a * sw2;
      float* hr = Hbuf + (size_t)grow * N + n0 + wn * 64 + (lane & 15);
#pragma unroll
      for (int j = 0; j < 4; ++j) {
        const float y1 = acc1[i][j][qe] * f1;
        const float y2 = acc2[i][j][qe] * f2;
        const float g = y1 / (1.0f + expf(-y1));  // silu
        hr[j * 16] = g * y2;
      }
    }
  }
}

// ---------------- down GEMM: Out = Q2 * W3^T, dequant epilogue ----------------
__launch_bounds__(256, 2)
__global__ void gemm_down(const unsigned short* __restrict__ Aq,   // [Mc][K]
                          const unsigned short* __restrict__ Wq,   // [N][K]
                          const float* __restrict__ arow,
                          const double* __restrict__ wsum,
                          float* __restrict__ Out,                 // [Mc][N] fp32
                          const int N, const int K) {
  __shared__ __align__(16) unsigned short lA[BM * BK];
  __shared__ __align__(16) unsigned short lB[BN * BK];

  const int tid = threadIdx.x;
  const int lane = tid & 63;
  const int wid = tid >> 6;
  const int wm = wid >> 1, wn = wid & 1;
  const int m0 = blockIdx.y * BM;
  const int n0 = blockIdx.x * BN;

  const double inv_n = 1.0 / 11534336.0;
  const float sw3 = (float)fmax(wsum[2] * inv_n, (double)EPSQ);

  f32x4 acc[4][4] = {};

  const size_t Kb = (size_t)K * 2;
  const int so = wid * 2048;
  const char* Ab = (const char*)Aq + (size_t)m0 * Kb;
  const char* Bb = (const char*)Wq + (size_t)n0 * Kb;

  for (int k0 = 0; k0 < K; k0 += BK) {
#pragma unroll
    for (int t = 0; t < 2; ++t) {
      const int o = so + t * 1024 + lane * 16;
      const int r = o >> 6;
      const int cb = o & 63;
      const size_t goff = (size_t)r * Kb + (size_t)k0 * 2 + (size_t)cb;
      gload_lds16(Ab + goff, (char*)lA + so + t * 1024);
      gload_lds16(Bb + goff, (char*)lB + so + t * 1024);
    }
    __syncthreads();

    const unsigned short* pa = lA + (wm * 64 + (lane & 15)) * BK + (lane >> 4) * 8;
    const unsigned short* pb = lB + (wn * 64 + (lane & 15)) * BK + (lane >> 4) * 8;
    bf16x8 af[4];
#pragma unroll
    for (int i = 0; i < 4; ++i) af[i] = *(const bf16x8*)(pa + i * 16 * BK);
#pragma unroll
    for (int j = 0; j < 4; ++j) {
      bf16x8 b = *(const bf16x8*)(pb + j * 16 * BK);
#pragma unroll
      for (int i = 0; i < 4; ++i) {
        acc[i][j] = __builtin_amdgcn_mfma_f32_16x16x32_bf16(af[i], b, acc[i][j], 0, 0, 0);
      }
    }
    __syncthreads();
  }

#pragma unroll
  for (int i = 0; i < 4; ++i) {
    const int rb = m0 + wm * 64 + i * 16 + (lane >> 4) * 4;
#pragma unroll
    for (int qe = 0; qe < 4; ++qe) {
      const int grow = rb + qe;
      const float f = arow[grow] * sw3;
      float* orow = Out + (size_t)grow * N + n0 + wn * 64 + (lane & 15);
#pragma unroll
      for (int j = 0; j < 4; ++j) {
        orow[j * 16] = acc[i][j][qe] * f;
      }
    }
  }
}

extern "C" void kernel_launch(void* const* d_in, const int* in_sizes, int n_in,
                              void* d_out, int out_size, void* d_ws, size_t ws_size,
                              hipStream_t stream) {
  (void)n_in; (void)out_size;
  const float* x  = (const float*)d_in[0];
  const float* w1 = (const float*)d_in[1];
  const float* w2 = (const float*)d_in[2];
  const float* w3 = (const float*)d_in[3];
  float* out = (float*)d_out;

  const int D = 2048, H = 5632;
  const int M = in_sizes[0] / D;             // 8192
  const long long NW = (long long)H * D;     // 11534336

  auto al = [](size_t v) { return (v + 255) & ~(size_t)255; };

  // fixed region: wsum + quantized weights (69.3 MB)
  size_t off = 0;
  const size_t o_wsum = off; off += al(3 * sizeof(double));
  const size_t o_w1q  = off; off += al((size_t)NW * 2);
  const size_t o_w2q  = off; off += al((size_t)NW * 2);
  const size_t o_w3q  = off; off += al((size_t)NW * 2);
  const size_t fixed = off;

  // adaptive chunk size: largest Mc (multiple of 128, power-of-2 fractions of M)
  // whose per-chunk buffers fit in the remaining workspace. Deterministic.
  int Mc = 128;
  for (int cand = M; cand >= 128; cand >>= 1) {
    size_t need = fixed
                + al((size_t)cand * 4)          // arow1
                + al((size_t)cand * 4)          // arow2
                + al((size_t)cand * D * 2)      // qx
                + al((size_t)cand * H * 4)      // hbuf fp32
                + al((size_t)cand * H * 2);     // qh
    if (need <= ws_size) { Mc = cand; break; }
  }

  size_t coff = fixed;
  const size_t o_arow1 = coff; coff += al((size_t)Mc * 4);
  const size_t o_arow2 = coff; coff += al((size_t)Mc * 4);
  const size_t o_qx    = coff; coff += al((size_t)Mc * D * 2);
  const size_t o_hbuf  = coff; coff += al((size_t)Mc * H * 4);
  const size_t o_qh    = coff; coff += al((size_t)Mc * H * 2);

  char* ws = (char*)d_ws;
  double* wsum        = (double*)(ws + o_wsum);
  unsigned short* w1q = (unsigned short*)(ws + o_w1q);
  unsigned short* w2q = (unsigned short*)(ws + o_w2q);
  unsigned short* w3q = (unsigned short*)(ws + o_w3q);
  float* arow1        = (float*)(ws + o_arow1);
  float* arow2        = (float*)(ws + o_arow2);
  unsigned short* qx  = (unsigned short*)(ws + o_qx);
  float* hbuf         = (float*)(ws + o_hbuf);
  unsigned short* qh  = (unsigned short*)(ws + o_qh);

  hipMemsetAsync(wsum, 0, 3 * sizeof(double), stream);

  const int n4w = (int)(NW / 4);                 // 2883584
  wabs_kernel<<<2048, 256, 0, stream>>>(w1, n4w, wsum + 0);
  wabs_kernel<<<2048, 256, 0, stream>>>(w2, n4w, wsum + 1);
  wabs_kernel<<<2048, 256, 0, stream>>>(w3, n4w, wsum + 2);

  const double inv_n = 1.0 / (double)NW;
  wquant_kernel<<<n4w / 256, 256, 0, stream>>>(w1, n4w, wsum + 0, inv_n, w1q);
  wquant_kernel<<<n4w / 256, 256, 0, stream>>>(w2, n4w, wsum + 1, inv_n, w2q);
  wquant_kernel<<<n4w / 256, 256, 0, stream>>>(w3, n4w, wsum + 2, inv_n, w3q);

  for (int c = 0; c < M; c += Mc) {
    aquant_kernel<<<Mc, 256, 0, stream>>>(x + (size_t)c * D, D, qx, arow1);
    gemm_gateup<<<dim3(H / BN, Mc / BM), 256, 0, stream>>>(qx, w1q, w2q, arow1, wsum,
                                                           hbuf, H, D);
    aquant_kernel<<<Mc, 256, 0, stream>>>(hbuf, H, qh, arow2);
    gemm_down<<<dim3(D / BN, Mc / BM), 256, 0, stream>>>(qh, w3q, arow2, wsum,
                                                         out + (size_t)c * D, D, H);
  }
}

// Round 3
// 581.810 us; speedup vs baseline: 1.6256x; 1.6256x over previous
//
#include <hip/hip_runtime.h>
#include <hip/hip_bf16.h>
#include <math.h>

#define EPSQ 1e-5f

typedef __attribute__((ext_vector_type(4))) int i32x4;

__device__ __forceinline__ void gload_lds16(const void* g, void* l) {
  __builtin_amdgcn_global_load_lds(
      (__attribute__((address_space(1))) void*)g,
      (__attribute__((address_space(3))) void*)l, 16, 0, 0);
}

__device__ __forceinline__ int clampi8(float v, float lo, float hi) {
  return (int)rintf(fminf(hi, fmaxf(lo, v)));
}

// ---------------- weight |w| sum (double, deterministic to ~1e-15) ----------------
__global__ void wabs_kernel(const float* __restrict__ w, int n4, double* __restrict__ sum) {
  __shared__ double sm[256];
  const float4* w4 = (const float4*)w;
  double acc = 0.0;
  const int stride = gridDim.x * blockDim.x;
  for (int i = blockIdx.x * blockDim.x + threadIdx.x; i < n4; i += stride) {
    float4 v = w4[i];
    acc += (double)fabsf(v.x) + (double)fabsf(v.y) + (double)fabsf(v.z) + (double)fabsf(v.w);
  }
  sm[threadIdx.x] = acc;
  __syncthreads();
  for (int s = 128; s > 0; s >>= 1) {
    if ((int)threadIdx.x < s) sm[threadIdx.x] += sm[threadIdx.x + s];
    __syncthreads();
  }
  if (threadIdx.x == 0) atomicAdd(sum, sm[0]);
}

// ---------------- ternary weight quant -> int8 {-1,0,1}, packed 4/word ----------------
__global__ void wquant_kernel(const float* __restrict__ w, int n4,
                              const double* __restrict__ sum, double inv_n,
                              unsigned int* __restrict__ wq) {
  const float s = (float)fmax(*sum * inv_n, (double)EPSQ);
  const float scale = 1.0f / s;  // same fp32 division as the reference
  const int i = blockIdx.x * blockDim.x + threadIdx.x;
  if (i >= n4) return;
  float4 v = ((const float4*)w)[i];
  const int b0 = clampi8(rintf(v.x * scale), -1.f, 1.f);
  const int b1 = clampi8(rintf(v.y * scale), -1.f, 1.f);
  const int b2 = clampi8(rintf(v.z * scale), -1.f, 1.f);
  const int b3 = clampi8(rintf(v.w * scale), -1.f, 1.f);
  wq[i] = (unsigned int)((b0 & 0xff) | ((b1 & 0xff) << 8) |
                         ((b2 & 0xff) << 16) | ((b3 & 0xff) << 24));
}

// ---------------- per-token absmax int8 quant, one block/row ----------------
__global__ void aquant_kernel(const float* __restrict__ x, int K,
                              unsigned char* __restrict__ q, float* __restrict__ arow) {
  const int row = blockIdx.x;
  const int n4 = K >> 2;
  const float4* xr = (const float4*)(x + (size_t)row * K);
  float m = 0.f;
  for (int c = threadIdx.x; c < n4; c += blockDim.x) {
    float4 v = xr[c];
    m = fmaxf(m, fmaxf(fmaxf(fabsf(v.x), fabsf(v.y)), fmaxf(fabsf(v.z), fabsf(v.w))));
  }
  __shared__ float sm[256];
  sm[threadIdx.x] = m;
  __syncthreads();
  for (int s = 128; s > 0; s >>= 1) {
    if ((int)threadIdx.x < s) sm[threadIdx.x] = fmaxf(sm[threadIdx.x], sm[threadIdx.x + s]);
    __syncthreads();
  }
  const float mv = fmaxf(sm[0], EPSQ);
  const float scale = 127.0f / mv;   // same fp32 division as the reference
  if (threadIdx.x == 0) arow[row] = mv * (1.0f / 127.0f);
  unsigned int* qr = (unsigned int*)(q + (size_t)row * K);
  for (int c = threadIdx.x; c < n4; c += blockDim.x) {
    float4 v = xr[c];
    const int b0 = clampi8(v.x * scale, -128.f, 127.f);
    const int b1 = clampi8(v.y * scale, -128.f, 127.f);
    const int b2 = clampi8(v.z * scale, -128.f, 127.f);
    const int b3 = clampi8(v.w * scale, -128.f, 127.f);
    qr[c] = (unsigned int)((b0 & 0xff) | ((b1 & 0xff) << 8) |
                           ((b2 & 0xff) << 16) | ((b3 & 0xff) << 24));
  }
}

// ---------------- fused gate/up GEMM (int8): H = silu(y1)*y2 ----------------
// Tile 128x128, BK=64 i8 (same 64-byte LDS rows as the bf16/BK=32 version).
#define BM 128
#define BN 128
#define BKI 64

__launch_bounds__(256, 2)
__global__ void gemm_gateup(const unsigned char* __restrict__ Aq,   // [Mc][K] i8
                            const unsigned char* __restrict__ W1q,  // [N][K] i8 ternary
                            const unsigned char* __restrict__ W2q,  // [N][K]
                            const float* __restrict__ arow,         // [Mc] = rowmax/127
                            const double* __restrict__ wsum,
                            float* __restrict__ Hbuf,               // [Mc][N] fp32
                            const int N, const int K) {
  __shared__ __align__(16) unsigned char lA[BM * BKI];
  __shared__ __align__(16) unsigned char lB1[BN * BKI];
  __shared__ __align__(16) unsigned char lB2[BN * BKI];

  const int tid = threadIdx.x;
  const int lane = tid & 63;
  const int wid = tid >> 6;           // 4 waves: 2x2 over 128x128, each 64x64
  const int wm = wid >> 1, wn = wid & 1;
  const int m0 = blockIdx.y * BM;
  const int n0 = blockIdx.x * BN;

  const double inv_n = 1.0 / 11534336.0;
  const float sw1 = (float)fmax(wsum[0] * inv_n, (double)EPSQ);
  const float sw2 = (float)fmax(wsum[1] * inv_n, (double)EPSQ);

  i32x4 acc1[4][4] = {};
  i32x4 acc2[4][4] = {};

  const int so = wid * 2048;          // this wave's 2KB slice per 8KB tile
  const unsigned char* Ab  = Aq  + (size_t)m0 * K;
  const unsigned char* B1b = W1q + (size_t)n0 * K;
  const unsigned char* B2b = W2q + (size_t)n0 * K;

  for (int k0 = 0; k0 < K; k0 += BKI) {
#pragma unroll
    for (int t = 0; t < 2; ++t) {
      const int o = so + t * 1024 + lane * 16;   // linear byte offset in [128][64B] tile
      const int r = o >> 6;
      const int cb = o & 63;
      const size_t goff = (size_t)r * K + (size_t)k0 + (size_t)cb;
      // LDS dest is wave-uniform; HW adds lane*16
      gload_lds16(Ab  + goff, (char*)lA  + so + t * 1024);
      gload_lds16(B1b + goff, (char*)lB1 + so + t * 1024);
      gload_lds16(B2b + goff, (char*)lB2 + so + t * 1024);
    }
    __syncthreads();

    const unsigned char* pa  = lA  + (wm * 64 + (lane & 15)) * BKI + (lane >> 4) * 16;
    const unsigned char* pb1 = lB1 + (wn * 64 + (lane & 15)) * BKI + (lane >> 4) * 16;
    const unsigned char* pb2 = lB2 + (wn * 64 + (lane & 15)) * BKI + (lane >> 4) * 16;
    i32x4 af[4];
#pragma unroll
    for (int i = 0; i < 4; ++i) af[i] = *(const i32x4*)(pa + i * 16 * BKI);
#pragma unroll
    for (int j = 0; j < 4; ++j) {
      i32x4 b1 = *(const i32x4*)(pb1 + j * 16 * BKI);
      i32x4 b2 = *(const i32x4*)(pb2 + j * 16 * BKI);
#pragma unroll
      for (int i = 0; i < 4; ++i) {
        acc1[i][j] = __builtin_amdgcn_mfma_i32_16x16x64_i8(af[i], b1, acc1[i][j], 0, 0, 0);
        acc2[i][j] = __builtin_amdgcn_mfma_i32_16x16x64_i8(af[i], b2, acc2[i][j], 0, 0, 0);
      }
    }
    __syncthreads();
  }

  // epilogue: dequant + silu(gate)*up, write fp32 H
#pragma unroll
  for (int i = 0; i < 4; ++i) {
    const int rb = m0 + wm * 64 + i * 16 + (lane >> 4) * 4;
#pragma unroll
    for (int qe = 0; qe < 4; ++qe) {
      const int grow = rb + qe;
      const float a = arow[grow];
      const float f1 = a * sw1;
      const float f2 = a * sw2;
      float* hr = Hbuf + (size_t)grow * N + n0 + wn * 64 + (lane & 15);
#pragma unroll
      for (int j = 0; j < 4; ++j) {
        const float y1 = (float)acc1[i][j][qe] * f1;
        const float y2 = (float)acc2[i][j][qe] * f2;
        const float g = y1 / (1.0f + expf(-y1));  // silu
        hr[j * 16] = g * y2;
      }
    }
  }
}

// ---------------- down GEMM (int8): Out = Q2 * W3^T, dequant epilogue ----------------
__launch_bounds__(256, 2)
__global__ void gemm_down(const unsigned char* __restrict__ Aq,   // [Mc][K] i8
                          const unsigned char* __restrict__ Wq,   // [N][K] i8 ternary
                          const float* __restrict__ arow,
                          const double* __restrict__ wsum,
                          float* __restrict__ Out,                // [Mc][N] fp32
                          const int N, const int K) {
  __shared__ __align__(16) unsigned char lA[BM * BKI];
  __shared__ __align__(16) unsigned char lB[BN * BKI];

  const int tid = threadIdx.x;
  const int lane = tid & 63;
  const int wid = tid >> 6;
  const int wm = wid >> 1, wn = wid & 1;
  const int m0 = blockIdx.y * BM;
  const int n0 = blockIdx.x * BN;

  const double inv_n = 1.0 / 11534336.0;
  const float sw3 = (float)fmax(wsum[2] * inv_n, (double)EPSQ);

  i32x4 acc[4][4] = {};

  const int so = wid * 2048;
  const unsigned char* Ab = Aq + (size_t)m0 * K;
  const unsigned char* Bb = Wq + (size_t)n0 * K;

  for (int k0 = 0; k0 < K; k0 += BKI) {
#pragma unroll
    for (int t = 0; t < 2; ++t) {
      const int o = so + t * 1024 + lane * 16;
      const int r = o >> 6;
      const int cb = o & 63;
      const size_t goff = (size_t)r * K + (size_t)k0 + (size_t)cb;
      gload_lds16(Ab + goff, (char*)lA + so + t * 1024);
      gload_lds16(Bb + goff, (char*)lB + so + t * 1024);
    }
    __syncthreads();

    const unsigned char* pa = lA + (wm * 64 + (lane & 15)) * BKI + (lane >> 4) * 16;
    const unsigned char* pb = lB + (wn * 64 + (lane & 15)) * BKI + (lane >> 4) * 16;
    i32x4 af[4];
#pragma unroll
    for (int i = 0; i < 4; ++i) af[i] = *(const i32x4*)(pa + i * 16 * BKI);
#pragma unroll
    for (int j = 0; j < 4; ++j) {
      i32x4 b = *(const i32x4*)(pb + j * 16 * BKI);
#pragma unroll
      for (int i = 0; i < 4; ++i) {
        acc[i][j] = __builtin_amdgcn_mfma_i32_16x16x64_i8(af[i], b, acc[i][j], 0, 0, 0);
      }
    }
    __syncthreads();
  }

#pragma unroll
  for (int i = 0; i < 4; ++i) {
    const int rb = m0 + wm * 64 + i * 16 + (lane >> 4) * 4;
#pragma unroll
    for (int qe = 0; qe < 4; ++qe) {
      const int grow = rb + qe;
      const float f = arow[grow] * sw3;
      float* orow = Out + (size_t)grow * N + n0 + wn * 64 + (lane & 15);
#pragma unroll
      for (int j = 0; j < 4; ++j) {
        orow[j * 16] = (float)acc[i][j][qe] * f;
      }
    }
  }
}

extern "C" void kernel_launch(void* const* d_in, const int* in_sizes, int n_in,
                              void* d_out, int out_size, void* d_ws, size_t ws_size,
                              hipStream_t stream) {
  (void)n_in; (void)out_size;
  const float* x  = (const float*)d_in[0];
  const float* w1 = (const float*)d_in[1];
  const float* w2 = (const float*)d_in[2];
  const float* w3 = (const float*)d_in[3];
  float* out = (float*)d_out;

  const int D = 2048, H = 5632;
  const int M = in_sizes[0] / D;             // 8192
  const long long NW = (long long)H * D;     // 11534336

  auto al = [](size_t v) { return (v + 255) & ~(size_t)255; };

  // fixed region: wsum + int8 quantized weights (34.6 MB)
  size_t off = 0;
  const size_t o_wsum = off; off += al(3 * sizeof(double));
  const size_t o_w1q  = off; off += al((size_t)NW);
  const size_t o_w2q  = off; off += al((size_t)NW);
  const size_t o_w3q  = off; off += al((size_t)NW);
  const size_t fixed = off;

  // adaptive chunk size: largest Mc (multiple of 128, power-of-2 fraction of M)
  // whose per-chunk buffers fit. Deterministic given ws_size.
  int Mc = 128;
  for (int cand = M; cand >= 128; cand >>= 1) {
    size_t need = fixed
                + al((size_t)cand * 4)          // arow1
                + al((size_t)cand * 4)          // arow2
                + al((size_t)cand * D)          // qx i8
                + al((size_t)cand * H * 4)      // hbuf fp32
                + al((size_t)cand * H);         // qh i8
    if (need <= ws_size) { Mc = cand; break; }
  }

  size_t coff = fixed;
  const size_t o_arow1 = coff; coff += al((size_t)Mc * 4);
  const size_t o_arow2 = coff; coff += al((size_t)Mc * 4);
  const size_t o_qx    = coff; coff += al((size_t)Mc * D);
  const size_t o_hbuf  = coff; coff += al((size_t)Mc * H * 4);
  const size_t o_qh    = coff; coff += al((size_t)Mc * H);

  char* ws = (char*)d_ws;
  double* wsum        = (double*)(ws + o_wsum);
  unsigned char* w1q  = (unsigned char*)(ws + o_w1q);
  unsigned char* w2q  = (unsigned char*)(ws + o_w2q);
  unsigned char* w3q  = (unsigned char*)(ws + o_w3q);
  float* arow1        = (float*)(ws + o_arow1);
  float* arow2        = (float*)(ws + o_arow2);
  unsigned char* qx   = (unsigned char*)(ws + o_qx);
  float* hbuf         = (float*)(ws + o_hbuf);
  unsigned char* qh   = (unsigned char*)(ws + o_qh);

  hipMemsetAsync(wsum, 0, 3 * sizeof(double), stream);

  const int n4w = (int)(NW / 4);                 // 2883584
  wabs_kernel<<<2048, 256, 0, stream>>>(w1, n4w, wsum + 0);
  wabs_kernel<<<2048, 256, 0, stream>>>(w2, n4w, wsum + 1);
  wabs_kernel<<<2048, 256, 0, stream>>>(w3, n4w, wsum + 2);

  const double inv_n = 1.0 / (double)NW;
  wquant_kernel<<<n4w / 256, 256, 0, stream>>>(w1, n4w, wsum + 0, inv_n, (unsigned int*)w1q);
  wquant_kernel<<<n4w / 256, 256, 0, stream>>>(w2, n4w, wsum + 1, inv_n, (unsigned int*)w2q);
  wquant_kernel<<<n4w / 256, 256, 0, stream>>>(w3, n4w, wsum + 2, inv_n, (unsigned int*)w3q);

  for (int c = 0; c < M; c += Mc) {
    aquant_kernel<<<Mc, 256, 0, stream>>>(x + (size_t)c * D, D, qx, arow1);
    gemm_gateup<<<dim3(H / BN, Mc / BM), 256, 0, stream>>>(qx, w1q, w2q, arow1, wsum,
                                                           hbuf, H, D);
    aquant_kernel<<<Mc, 256, 0, stream>>>(hbuf, H, qh, arow2);
    gemm_down<<<dim3(D / BN, Mc / BM), 256, 0, stream>>>(qh, w3q, arow2, wsum,
                                                         out + (size_t)c * D, D, H);
  }
}

// Round 4
// 532.257 us; speedup vs baseline: 1.7770x; 1.0931x over previous
//
#include <hip/hip_runtime.h>
#include <hip/hip_bf16.h>
#include <math.h>

#define EPSQ 1e-5f

typedef __attribute__((ext_vector_type(4))) int i32x4;

__device__ __forceinline__ void gload_lds16(const void* g, void* l) {
  __builtin_amdgcn_global_load_lds(
      (__attribute__((address_space(1))) void*)g,
      (__attribute__((address_space(3))) void*)l, 16, 0, 0);
}

__device__ __forceinline__ int clampi8(float v, float lo, float hi) {
  return (int)rintf(fminf(hi, fmaxf(lo, v)));
}

// ---------------- weight |w| sum (double, deterministic to ~1e-15) ----------------
__global__ void wabs_kernel(const float* __restrict__ w, int n4, double* __restrict__ sum) {
  __shared__ double sm[256];
  const float4* w4 = (const float4*)w;
  double acc = 0.0;
  const int stride = gridDim.x * blockDim.x;
  for (int i = blockIdx.x * blockDim.x + threadIdx.x; i < n4; i += stride) {
    float4 v = w4[i];
    acc += (double)fabsf(v.x) + (double)fabsf(v.y) + (double)fabsf(v.z) + (double)fabsf(v.w);
  }
  sm[threadIdx.x] = acc;
  __syncthreads();
  for (int s = 128; s > 0; s >>= 1) {
    if ((int)threadIdx.x < s) sm[threadIdx.x] += sm[threadIdx.x + s];
    __syncthreads();
  }
  if (threadIdx.x == 0) atomicAdd(sum, sm[0]);
}

// ---------------- ternary weight quant -> int8 {-1,0,1}, packed 4/word ----------------
__global__ void wquant_kernel(const float* __restrict__ w, int n4,
                              const double* __restrict__ sum, double inv_n,
                              unsigned int* __restrict__ wq) {
  const float s = (float)fmax(*sum * inv_n, (double)EPSQ);
  const float scale = 1.0f / s;  // same fp32 division as the reference
  const int i = blockIdx.x * blockDim.x + threadIdx.x;
  if (i >= n4) return;
  float4 v = ((const float4*)w)[i];
  const int b0 = clampi8(rintf(v.x * scale), -1.f, 1.f);
  const int b1 = clampi8(rintf(v.y * scale), -1.f, 1.f);
  const int b2 = clampi8(rintf(v.z * scale), -1.f, 1.f);
  const int b3 = clampi8(rintf(v.w * scale), -1.f, 1.f);
  wq[i] = (unsigned int)((b0 & 0xff) | ((b1 & 0xff) << 8) |
                         ((b2 & 0xff) << 16) | ((b3 & 0xff) << 24));
}

// ---------------- per-token absmax int8 quant, one block/row ----------------
__global__ void aquant_kernel(const float* __restrict__ x, int K,
                              unsigned char* __restrict__ q, float* __restrict__ arow) {
  const int row = blockIdx.x;
  const int n4 = K >> 2;
  const float4* xr = (const float4*)(x + (size_t)row * K);
  float m = 0.f;
  for (int c = threadIdx.x; c < n4; c += blockDim.x) {
    float4 v = xr[c];
    m = fmaxf(m, fmaxf(fmaxf(fabsf(v.x), fabsf(v.y)), fmaxf(fabsf(v.z), fabsf(v.w))));
  }
  __shared__ float sm[256];
  sm[threadIdx.x] = m;
  __syncthreads();
  for (int s = 128; s > 0; s >>= 1) {
    if ((int)threadIdx.x < s) sm[threadIdx.x] = fmaxf(sm[threadIdx.x], sm[threadIdx.x + s]);
    __syncthreads();
  }
  const float mv = fmaxf(sm[0], EPSQ);
  const float scale = 127.0f / mv;   // same fp32 division as the reference
  if (threadIdx.x == 0) arow[row] = mv * (1.0f / 127.0f);
  unsigned int* qr = (unsigned int*)(q + (size_t)row * K);
  for (int c = threadIdx.x; c < n4; c += blockDim.x) {
    float4 v = xr[c];
    const int b0 = clampi8(v.x * scale, -128.f, 127.f);
    const int b1 = clampi8(v.y * scale, -128.f, 127.f);
    const int b2 = clampi8(v.z * scale, -128.f, 127.f);
    const int b3 = clampi8(v.w * scale, -128.f, 127.f);
    qr[c] = (unsigned int)((b0 & 0xff) | ((b1 & 0xff) << 8) |
                           ((b2 & 0xff) << 16) | ((b3 & 0xff) << 24));
  }
}

// =================================================================================
// Pipelined i8 GEMMs: tile 256(M)x128(N), BK=64, 8 waves (4Mx2N, 64x64 each),
// triple-buffered LDS slots, counted vmcnt (never 0 in loop), raw s_barrier,
// XOR-swizzled LDS (both sides: pre-swizzled global src + swizzled ds_read).
// =================================================================================
#define BKP 64

// swizzle: slot' = slot ^ ((row>>1)&3); applied to 16B slots within 64B rows.

// barrier helpers (no implicit vmcnt(0)/lgkmcnt(0) drain)
#define PIPE_BARRIER(N)                                         \
  asm volatile("s_waitcnt vmcnt(" #N ")" ::: "memory");         \
  __builtin_amdgcn_s_barrier();                                 \
  asm volatile("" ::: "memory");

// ---------------- fused gate/up GEMM (int8, pipelined) ----------------
#define GU_SLOT 32768   // A 16KB + B1 8KB + B2 8KB

__launch_bounds__(512, 2)
__global__ void gemm_gateup(const unsigned char* __restrict__ Aq,   // [Mc][K] i8
                            const unsigned char* __restrict__ W1q,  // [N][K] i8 ternary
                            const unsigned char* __restrict__ W2q,  // [N][K]
                            const float* __restrict__ arow,         // [Mc] = rowmax/127
                            const double* __restrict__ wsum,
                            float* __restrict__ Hbuf,               // [Mc][N] fp32
                            const int N, const int K,
                            const int MBb, const int NBb) {
  __shared__ char lds[3 * GU_SLOT];   // 96 KiB

  const int tid = threadIdx.x;
  const int lane = tid & 63;
  const int wid = tid >> 6;          // 8 waves
  const int wm = wid >> 1;           // 0..3 (M)
  const int wn = wid & 1;            // 0..1 (N)

  // T1: XCD-aware block swizzle (bijective when total % 8 == 0)
  const int total = MBb * NBb;
  int swz = blockIdx.x;
  if ((total & 7) == 0) swz = (swz & 7) * (total >> 3) + (swz >> 3);
  const int nb = swz % NBb;          // nb fast: neighbors share the A panel
  const int mb = swz / NBb;
  const int m0 = mb * 256;
  const int n0 = nb * 128;

  const unsigned char* Ab  = Aq  + (size_t)m0 * K;
  const unsigned char* B1b = W1q + (size_t)n0 * K;
  const unsigned char* B2b = W2q + (size_t)n0 * K;

  // stage one K-tile into slot s: A 2 issues + B1 1 + B2 1 per wave (vmcnt +4)
  auto stage = [&](int kt, int s) {
    const int k0 = kt * BKP;
    char* base = lds + s * GU_SLOT;
#pragma unroll
    for (int is = 0; is < 2; ++is) {
      const int p = is * 8192 + wid * 1024 + lane * 16;   // phys byte in A region
      const int r = p >> 6;
      const int c = ((p >> 4) & 3) ^ ((r >> 1) & 3);      // inverse-swizzled source
      gload_lds16(Ab + (size_t)r * K + k0 + c * 16, base + is * 8192 + wid * 1024);
    }
    {
      const int p = wid * 1024 + lane * 16;
      const int r = p >> 6;
      const int c = ((p >> 4) & 3) ^ ((r >> 1) & 3);
      const size_t go = (size_t)r * K + k0 + c * 16;
      gload_lds16(B1b + go, base + 16384 + wid * 1024);
      gload_lds16(B2b + go, base + 24576 + wid * 1024);
    }
  };

  // precomputed swizzled read offsets (K-invariant)
  const int c16 = lane >> 4;
  int offA[4], offB1[4], offB2[4];
#pragma unroll
  for (int i = 0; i < 4; ++i) {
    const int row = wm * 64 + i * 16 + (lane & 15);
    offA[i] = row * 64 + ((c16 ^ ((row >> 1) & 3)) << 4);
  }
#pragma unroll
  for (int j = 0; j < 4; ++j) {
    const int n = wn * 64 + j * 16 + (lane & 15);
    const int o = n * 64 + ((c16 ^ ((n >> 1) & 3)) << 4);
    offB1[j] = 16384 + o;
    offB2[j] = 24576 + o;
  }

  i32x4 acc1[4][4] = {};
  i32x4 acc2[4][4] = {};

  const int NT = K / BKP;
  stage(0, 0);
  stage(1, 1);
  PIPE_BARRIER(4)                    // tile 0 landed; tile 1 (4 issues) in flight

  int s = 0, s2 = 2;
  for (int t = 0; t < NT; ++t) {
    if (t + 2 < NT) stage(t + 2, s2);   // issue-early; slot of t-1 (read-complete)
    const char* sb = lds + s * GU_SLOT;
    i32x4 af[4], b1f[4], b2f[4];
#pragma unroll
    for (int i = 0; i < 4; ++i) af[i] = *(const i32x4*)(sb + offA[i]);
#pragma unroll
    for (int j = 0; j < 4; ++j) {
      b1f[j] = *(const i32x4*)(sb + offB1[j]);
      b2f[j] = *(const i32x4*)(sb + offB2[j]);
    }
    __builtin_amdgcn_s_setprio(1);
#pragma unroll
    for (int j = 0; j < 4; ++j)
#pragma unroll
      for (int i = 0; i < 4; ++i) {
        acc1[i][j] = __builtin_amdgcn_mfma_i32_16x16x64_i8(af[i], b1f[j], acc1[i][j], 0, 0, 0);
        acc2[i][j] = __builtin_amdgcn_mfma_i32_16x16x64_i8(af[i], b2f[j], acc2[i][j], 0, 0, 0);
      }
    __builtin_amdgcn_s_setprio(0);
    if (t + 2 < NT) {
      PIPE_BARRIER(4)                // t+1 landed; t+2 stays in flight
    } else if (t + 1 < NT) {
      PIPE_BARRIER(0)                // tail: drain last tile
    }
    s = (s == 2) ? 0 : s + 1;
    s2 = (s2 == 2) ? 0 : s2 + 1;
  }

  // epilogue: dequant + silu(gate)*up, write fp32 H
  const double inv_n = 1.0 / 11534336.0;
  const float sw1 = (float)fmax(wsum[0] * inv_n, (double)EPSQ);
  const float sw2 = (float)fmax(wsum[1] * inv_n, (double)EPSQ);
#pragma unroll
  for (int i = 0; i < 4; ++i) {
    const int rb = m0 + wm * 64 + i * 16 + (lane >> 4) * 4;
#pragma unroll
    for (int qe = 0; qe < 4; ++qe) {
      const int grow = rb + qe;
      const float a = arow[grow];
      const float f1 = a * sw1;
      const float f2 = a * sw2;
      float* hr = Hbuf + (size_t)grow * N + n0 + wn * 64 + (lane & 15);
#pragma unroll
      for (int j = 0; j < 4; ++j) {
        const float y1 = (float)acc1[i][j][qe] * f1;
        const float y2 = (float)acc2[i][j][qe] * f2;
        hr[j * 16] = (y1 / (1.0f + expf(-y1))) * y2;   // silu(y1)*y2
      }
    }
  }
}

// ---------------- down GEMM (int8, pipelined): Out = Q2 * W3^T ----------------
#define DN_SLOT 24576   // A 16KB + B 8KB

__launch_bounds__(512, 2)
__global__ void gemm_down(const unsigned char* __restrict__ Aq,   // [Mc][K] i8
                          const unsigned char* __restrict__ Wq,   // [N][K] i8 ternary
                          const float* __restrict__ arow,
                          const double* __restrict__ wsum,
                          float* __restrict__ Out,                // [Mc][N] fp32
                          const int N, const int K,
                          const int MBb, const int NBb) {
  __shared__ char lds[3 * DN_SLOT];   // 72 KiB

  const int tid = threadIdx.x;
  const int lane = tid & 63;
  const int wid = tid >> 6;
  const int wm = wid >> 1;
  const int wn = wid & 1;

  const int total = MBb * NBb;
  int swz = blockIdx.x;
  if ((total & 7) == 0) swz = (swz & 7) * (total >> 3) + (swz >> 3);
  const int nb = swz % NBb;
  const int mb = swz / NBb;
  const int m0 = mb * 256;
  const int n0 = nb * 128;

  const unsigned char* Ab = Aq + (size_t)m0 * K;
  const unsigned char* Bb = Wq + (size_t)n0 * K;

  auto stage = [&](int kt, int s) {
    const int k0 = kt * BKP;
    char* base = lds + s * DN_SLOT;
#pragma unroll
    for (int is = 0; is < 2; ++is) {
      const int p = is * 8192 + wid * 1024 + lane * 16;
      const int r = p >> 6;
      const int c = ((p >> 4) & 3) ^ ((r >> 1) & 3);
      gload_lds16(Ab + (size_t)r * K + k0 + c * 16, base + is * 8192 + wid * 1024);
    }
    {
      const int p = wid * 1024 + lane * 16;
      const int r = p >> 6;
      const int c = ((p >> 4) & 3) ^ ((r >> 1) & 3);
      gload_lds16(Bb + (size_t)r * K + k0 + c * 16, base + 16384 + wid * 1024);
    }
  };

  const int c16 = lane >> 4;
  int offA[4], offB[4];
#pragma unroll
  for (int i = 0; i < 4; ++i) {
    const int row = wm * 64 + i * 16 + (lane & 15);
    offA[i] = row * 64 + ((c16 ^ ((row >> 1) & 3)) << 4);
  }
#pragma unroll
  for (int j = 0; j < 4; ++j) {
    const int n = wn * 64 + j * 16 + (lane & 15);
    offB[j] = 16384 + n * 64 + ((c16 ^ ((n >> 1) & 3)) << 4);
  }

  i32x4 acc[4][4] = {};

  const int NT = K / BKP;
  stage(0, 0);
  stage(1, 1);
  PIPE_BARRIER(3)                    // 6 issued; tile 0 (3) landed

  int s = 0, s2 = 2;
  for (int t = 0; t < NT; ++t) {
    if (t + 2 < NT) stage(t + 2, s2);
    const char* sb = lds + s * DN_SLOT;
    i32x4 af[4], bf[4];
#pragma unroll
    for (int i = 0; i < 4; ++i) af[i] = *(const i32x4*)(sb + offA[i]);
#pragma unroll
    for (int j = 0; j < 4; ++j) bf[j] = *(const i32x4*)(sb + offB[j]);
    __builtin_amdgcn_s_setprio(1);
#pragma unroll
    for (int j = 0; j < 4; ++j)
#pragma unroll
      for (int i = 0; i < 4; ++i)
        acc[i][j] = __builtin_amdgcn_mfma_i32_16x16x64_i8(af[i], bf[j], acc[i][j], 0, 0, 0);
    __builtin_amdgcn_s_setprio(0);
    if (t + 2 < NT) {
      PIPE_BARRIER(3)
    } else if (t + 1 < NT) {
      PIPE_BARRIER(0)
    }
    s = (s == 2) ? 0 : s + 1;
    s2 = (s2 == 2) ? 0 : s2 + 1;
  }

  const double inv_n = 1.0 / 11534336.0;
  const float sw3 = (float)fmax(wsum[2] * inv_n, (double)EPSQ);
#pragma unroll
  for (int i = 0; i < 4; ++i) {
    const int rb = m0 + wm * 64 + i * 16 + (lane >> 4) * 4;
#pragma unroll
    for (int qe = 0; qe < 4; ++qe) {
      const int grow = rb + qe;
      const float f = arow[grow] * sw3;
      float* orow = Out + (size_t)grow * N + n0 + wn * 64 + (lane & 15);
#pragma unroll
      for (int j = 0; j < 4; ++j) {
        orow[j * 16] = (float)acc[i][j][qe] * f;
      }
    }
  }
}

extern "C" void kernel_launch(void* const* d_in, const int* in_sizes, int n_in,
                              void* d_out, int out_size, void* d_ws, size_t ws_size,
                              hipStream_t stream) {
  (void)n_in; (void)out_size;
  const float* x  = (const float*)d_in[0];
  const float* w1 = (const float*)d_in[1];
  const float* w2 = (const float*)d_in[2];
  const float* w3 = (const float*)d_in[3];
  float* out = (float*)d_out;

  const int D = 2048, H = 5632;
  const int M = in_sizes[0] / D;             // 8192
  const long long NW = (long long)H * D;     // 11534336

  auto al = [](size_t v) { return (v + 255) & ~(size_t)255; };

  // fixed region: wsum + int8 quantized weights (34.6 MB)
  size_t off = 0;
  const size_t o_wsum = off; off += al(3 * sizeof(double));
  const size_t o_w1q  = off; off += al((size_t)NW);
  const size_t o_w2q  = off; off += al((size_t)NW);
  const size_t o_w3q  = off; off += al((size_t)NW);
  const size_t fixed = off;

  // adaptive chunk size: largest Mc (multiple of 256, power-of-2 fraction of M)
  int Mc = 256;
  for (int cand = M; cand >= 256; cand >>= 1) {
    size_t need = fixed
                + al((size_t)cand * 4)          // arow1
                + al((size_t)cand * 4)          // arow2
                + al((size_t)cand * D)          // qx i8
                + al((size_t)cand * H * 4)      // hbuf fp32
                + al((size_t)cand * H);         // qh i8
    if (need <= ws_size) { Mc = cand; break; }
  }

  size_t coff = fixed;
  const size_t o_arow1 = coff; coff += al((size_t)Mc * 4);
  const size_t o_arow2 = coff; coff += al((size_t)Mc * 4);
  const size_t o_qx    = coff; coff += al((size_t)Mc * D);
  const size_t o_hbuf  = coff; coff += al((size_t)Mc * H * 4);
  const size_t o_qh    = coff; coff += al((size_t)Mc * H);

  char* ws = (char*)d_ws;
  double* wsum        = (double*)(ws + o_wsum);
  unsigned char* w1q  = (unsigned char*)(ws + o_w1q);
  unsigned char* w2q  = (unsigned char*)(ws + o_w2q);
  unsigned char* w3q  = (unsigned char*)(ws + o_w3q);
  float* arow1        = (float*)(ws + o_arow1);
  float* arow2        = (float*)(ws + o_arow2);
  unsigned char* qx   = (unsigned char*)(ws + o_qx);
  float* hbuf         = (float*)(ws + o_hbuf);
  unsigned char* qh   = (unsigned char*)(ws + o_qh);

  hipMemsetAsync(wsum, 0, 3 * sizeof(double), stream);

  const int n4w = (int)(NW / 4);                 // 2883584
  wabs_kernel<<<2048, 256, 0, stream>>>(w1, n4w, wsum + 0);
  wabs_kernel<<<2048, 256, 0, stream>>>(w2, n4w, wsum + 1);
  wabs_kernel<<<2048, 256, 0, stream>>>(w3, n4w, wsum + 2);

  const double inv_n = 1.0 / (double)NW;
  wquant_kernel<<<n4w / 256, 256, 0, stream>>>(w1, n4w, wsum + 0, inv_n, (unsigned int*)w1q);
  wquant_kernel<<<n4w / 256, 256, 0, stream>>>(w2, n4w, wsum + 1, inv_n, (unsigned int*)w2q);
  wquant_kernel<<<n4w / 256, 256, 0, stream>>>(w3, n4w, wsum + 2, inv_n, (unsigned int*)w3q);

  const int NBgu = H / 128;                      // 44
  const int NBdn = D / 128;                      // 16
  for (int c = 0; c < M; c += Mc) {
    const int MBb = Mc / 256;
    aquant_kernel<<<Mc, 256, 0, stream>>>(x + (size_t)c * D, D, qx, arow1);
    gemm_gateup<<<MBb * NBgu, 512, 0, stream>>>(qx, w1q, w2q, arow1, wsum,
                                                hbuf, H, D, MBb, NBgu);
    aquant_kernel<<<Mc, 256, 0, stream>>>(hbuf, H, qh, arow2);
    gemm_down<<<MBb * NBdn, 512, 0, stream>>>(qh, w3q, arow2, wsum,
                                              out + (size_t)c * D, D, H, MBb, NBdn);
  }
}

// Round 5
// 492.838 us; speedup vs baseline: 1.9191x; 1.0800x over previous
//
#include <hip/hip_runtime.h>
#include <hip/hip_bf16.h>
#include <math.h>

#define EPSQ 1e-5f

typedef __attribute__((ext_vector_type(4))) int i32x4;

__device__ __forceinline__ void gload_lds16(const void* g, void* l) {
  __builtin_amdgcn_global_load_lds(
      (__attribute__((address_space(1))) void*)g,
      (__attribute__((address_space(3))) void*)l, 16, 0, 0);
}

__device__ __forceinline__ int clampi8(float v, float lo, float hi) {
  return (int)rintf(fminf(hi, fmaxf(lo, v)));
}

// ---------------- fused weight |w| sums: one dispatch, 3 weights ----------------
__global__ void wabs3_kernel(const float* __restrict__ w1, const float* __restrict__ w2,
                             const float* __restrict__ w3, int n4,
                             double* __restrict__ sums) {
  const float* w = (blockIdx.y == 0) ? w1 : (blockIdx.y == 1) ? w2 : w3;
  __shared__ double sm[256];
  const float4* w4 = (const float4*)w;
  double acc = 0.0;
  const int stride = gridDim.x * blockDim.x;
  for (int i = blockIdx.x * blockDim.x + threadIdx.x; i < n4; i += stride) {
    float4 v = w4[i];
    acc += (double)fabsf(v.x) + (double)fabsf(v.y) + (double)fabsf(v.z) + (double)fabsf(v.w);
  }
  sm[threadIdx.x] = acc;
  __syncthreads();
  for (int s = 128; s > 0; s >>= 1) {
    if ((int)threadIdx.x < s) sm[threadIdx.x] += sm[threadIdx.x + s];
    __syncthreads();
  }
  if (threadIdx.x == 0) atomicAdd(sums + blockIdx.y, sm[0]);
}

// ---------------- fused ternary weight quant: one dispatch, 3 weights ----------------
__global__ void wquant3_kernel(const float* __restrict__ w1, const float* __restrict__ w2,
                               const float* __restrict__ w3, int n4,
                               const double* __restrict__ sums, double inv_n,
                               unsigned int* __restrict__ q1, unsigned int* __restrict__ q2,
                               unsigned int* __restrict__ q3) {
  const int wsel = blockIdx.y;
  const float* w = (wsel == 0) ? w1 : (wsel == 1) ? w2 : w3;
  unsigned int* wq = (wsel == 0) ? q1 : (wsel == 1) ? q2 : q3;
  const float s = (float)fmax(sums[wsel] * inv_n, (double)EPSQ);
  const float scale = 1.0f / s;  // same fp32 division as the reference
  const int i = blockIdx.x * blockDim.x + threadIdx.x;
  if (i >= n4) return;
  float4 v = ((const float4*)w)[i];
  const int b0 = clampi8(rintf(v.x * scale), -1.f, 1.f);
  const int b1 = clampi8(rintf(v.y * scale), -1.f, 1.f);
  const int b2 = clampi8(rintf(v.z * scale), -1.f, 1.f);
  const int b3 = clampi8(rintf(v.w * scale), -1.f, 1.f);
  wq[i] = (unsigned int)((b0 & 0xff) | ((b1 & 0xff) << 8) |
                         ((b2 & 0xff) << 16) | ((b3 & 0xff) << 24));
}

// ---------------- per-token absmax int8 quant (2-pass, for x) ----------------
__global__ void aquant_kernel(const float* __restrict__ x, int K,
                              unsigned char* __restrict__ q, float* __restrict__ arow) {
  const int row = blockIdx.x;
  const int n4 = K >> 2;
  const float4* xr = (const float4*)(x + (size_t)row * K);
  float m = 0.f;
  for (int c = threadIdx.x; c < n4; c += blockDim.x) {
    float4 v = xr[c];
    m = fmaxf(m, fmaxf(fmaxf(fabsf(v.x), fabsf(v.y)), fmaxf(fabsf(v.z), fabsf(v.w))));
  }
  __shared__ float sm[256];
  sm[threadIdx.x] = m;
  __syncthreads();
  for (int s = 128; s > 0; s >>= 1) {
    if ((int)threadIdx.x < s) sm[threadIdx.x] = fmaxf(sm[threadIdx.x], sm[threadIdx.x + s]);
    __syncthreads();
  }
  const float mv = fmaxf(sm[0], EPSQ);
  const float scale = 127.0f / mv;   // same fp32 division as the reference
  if (threadIdx.x == 0) arow[row] = mv * (1.0f / 127.0f);
  unsigned int* qr = (unsigned int*)(q + (size_t)row * K);
  for (int c = threadIdx.x; c < n4; c += blockDim.x) {
    float4 v = xr[c];
    const int b0 = clampi8(v.x * scale, -128.f, 127.f);
    const int b1 = clampi8(v.y * scale, -128.f, 127.f);
    const int b2 = clampi8(v.z * scale, -128.f, 127.f);
    const int b3 = clampi8(v.w * scale, -128.f, 127.f);
    qr[c] = (unsigned int)((b0 & 0xff) | ((b1 & 0xff) << 8) |
                           ((b2 & 0xff) << 16) | ((b3 & 0xff) << 24));
  }
}

// ---------------- single-pass quant for h: row max precomputed (raw) in arow ----------------
__global__ void aquant_pre_kernel(const float* __restrict__ x, int K,
                                  unsigned char* __restrict__ q, float* __restrict__ arow) {
  const int row = blockIdx.x;
  const float raw = arow[row];          // raw |h| row max from gemm_gateup atomics
  __syncthreads();
  const float mv = fmaxf(raw, EPSQ);
  const float scale = 127.0f / mv;
  if (threadIdx.x == 0) arow[row] = mv * (1.0f / 127.0f);
  const int n4 = K >> 2;
  const float4* xr = (const float4*)(x + (size_t)row * K);
  unsigned int* qr = (unsigned int*)(q + (size_t)row * K);
  for (int c = threadIdx.x; c < n4; c += blockDim.x) {
    float4 v = xr[c];
    const int b0 = clampi8(v.x * scale, -128.f, 127.f);
    const int b1 = clampi8(v.y * scale, -128.f, 127.f);
    const int b2 = clampi8(v.z * scale, -128.f, 127.f);
    const int b3 = clampi8(v.w * scale, -128.f, 127.f);
    qr[c] = (unsigned int)((b0 & 0xff) | ((b1 & 0xff) << 8) |
                           ((b2 & 0xff) << 16) | ((b3 & 0xff) << 24));
  }
}

// =================================================================================
// Pipelined i8 GEMMs: tile 256(M)x128(N), BK=64, 8 waves (4Mx2N, 64x64 each),
// triple-buffered LDS slots, counted vmcnt (never 0 in loop), raw s_barrier,
// XOR-swizzled LDS (both sides: pre-swizzled global src + swizzled ds_read).
// =================================================================================
#define BKP 64

#define PIPE_BARRIER(N)                                         \
  asm volatile("s_waitcnt vmcnt(" #N ")" ::: "memory");         \
  __builtin_amdgcn_s_barrier();                                 \
  asm volatile("" ::: "memory");

// ---------------- fused gate/up GEMM (int8, pipelined) ----------------
#define GU_SLOT 32768   // A 16KB + B1 8KB + B2 8KB

__launch_bounds__(512, 2)
__global__ void gemm_gateup(const unsigned char* __restrict__ Aq,   // [Mc][K] i8
                            const unsigned char* __restrict__ W1q,  // [N][K] i8 ternary
                            const unsigned char* __restrict__ W2q,  // [N][K]
                            const float* __restrict__ arow,         // [Mc] = rowmax/127
                            const double* __restrict__ wsum,
                            float* __restrict__ Hbuf,               // [Mc][N] fp32
                            float* __restrict__ hmax,               // [Mc] raw |h| max (atomic)
                            const int N, const int K,
                            const int MBb, const int NBb) {
  __shared__ char lds[3 * GU_SLOT];   // 96 KiB

  const int tid = threadIdx.x;
  const int lane = tid & 63;
  const int wid = tid >> 6;          // 8 waves
  const int wm = wid >> 1;           // 0..3 (M)
  const int wn = wid & 1;            // 0..1 (N)

  // T1: XCD-aware block swizzle (bijective when total % 8 == 0)
  const int total = MBb * NBb;
  int swz = blockIdx.x;
  if ((total & 7) == 0) swz = (swz & 7) * (total >> 3) + (swz >> 3);
  const int nb = swz % NBb;          // nb fast: neighbors share the A panel
  const int mb = swz / NBb;
  const int m0 = mb * 256;
  const int n0 = nb * 128;

  const unsigned char* Ab  = Aq  + (size_t)m0 * K;
  const unsigned char* B1b = W1q + (size_t)n0 * K;
  const unsigned char* B2b = W2q + (size_t)n0 * K;

  auto stage = [&](int kt, int s) {
    const int k0 = kt * BKP;
    char* base = lds + s * GU_SLOT;
#pragma unroll
    for (int is = 0; is < 2; ++is) {
      const int p = is * 8192 + wid * 1024 + lane * 16;   // phys byte in A region
      const int r = p >> 6;
      const int c = ((p >> 4) & 3) ^ ((r >> 1) & 3);      // inverse-swizzled source
      gload_lds16(Ab + (size_t)r * K + k0 + c * 16, base + is * 8192 + wid * 1024);
    }
    {
      const int p = wid * 1024 + lane * 16;
      const int r = p >> 6;
      const int c = ((p >> 4) & 3) ^ ((r >> 1) & 3);
      const size_t go = (size_t)r * K + k0 + c * 16;
      gload_lds16(B1b + go, base + 16384 + wid * 1024);
      gload_lds16(B2b + go, base + 24576 + wid * 1024);
    }
  };

  const int c16 = lane >> 4;
  int offA[4], offB1[4], offB2[4];
#pragma unroll
  for (int i = 0; i < 4; ++i) {
    const int row = wm * 64 + i * 16 + (lane & 15);
    offA[i] = row * 64 + ((c16 ^ ((row >> 1) & 3)) << 4);
  }
#pragma unroll
  for (int j = 0; j < 4; ++j) {
    const int n = wn * 64 + j * 16 + (lane & 15);
    const int o = n * 64 + ((c16 ^ ((n >> 1) & 3)) << 4);
    offB1[j] = 16384 + o;
    offB2[j] = 24576 + o;
  }

  i32x4 acc1[4][4] = {};
  i32x4 acc2[4][4] = {};

  const int NT = K / BKP;
  stage(0, 0);
  stage(1, 1);
  PIPE_BARRIER(4)                    // tile 0 landed; tile 1 (4 issues) in flight

  int s = 0, s2 = 2;
  for (int t = 0; t < NT; ++t) {
    if (t + 2 < NT) stage(t + 2, s2);   // issue-early; slot of t-1 (read-complete)
    const char* sb = lds + s * GU_SLOT;
    i32x4 af[4], b1f[4], b2f[4];
#pragma unroll
    for (int i = 0; i < 4; ++i) af[i] = *(const i32x4*)(sb + offA[i]);
#pragma unroll
    for (int j = 0; j < 4; ++j) {
      b1f[j] = *(const i32x4*)(sb + offB1[j]);
      b2f[j] = *(const i32x4*)(sb + offB2[j]);
    }
    __builtin_amdgcn_s_setprio(1);
#pragma unroll
    for (int j = 0; j < 4; ++j)
#pragma unroll
      for (int i = 0; i < 4; ++i) {
        acc1[i][j] = __builtin_amdgcn_mfma_i32_16x16x64_i8(af[i], b1f[j], acc1[i][j], 0, 0, 0);
        acc2[i][j] = __builtin_amdgcn_mfma_i32_16x16x64_i8(af[i], b2f[j], acc2[i][j], 0, 0, 0);
      }
    __builtin_amdgcn_s_setprio(0);
    if (t + 2 < NT) {
      PIPE_BARRIER(4)                // t+1 landed; t+2 stays in flight
    } else if (t + 1 < NT) {
      PIPE_BARRIER(0)                // tail: drain last tile
    }
    s = (s == 2) ? 0 : s + 1;
    s2 = (s2 == 2) ? 0 : s2 + 1;
  }

  // epilogue: dequant + silu(gate)*up, write fp32 H, and row |h| max via atomics
  const double inv_n = 1.0 / 11534336.0;
  const float sw1 = (float)fmax(wsum[0] * inv_n, (double)EPSQ);
  const float sw2 = (float)fmax(wsum[1] * inv_n, (double)EPSQ);
#pragma unroll
  for (int i = 0; i < 4; ++i) {
    const int rb = m0 + wm * 64 + i * 16 + (lane >> 4) * 4;
#pragma unroll
    for (int qe = 0; qe < 4; ++qe) {
      const int grow = rb + qe;
      const float a = arow[grow];
      const float f1 = a * sw1;
      const float f2 = a * sw2;
      float* hr = Hbuf + (size_t)grow * N + n0 + wn * 64 + (lane & 15);
      float lmax = 0.f;
#pragma unroll
      for (int j = 0; j < 4; ++j) {
        const float y1 = (float)acc1[i][j][qe] * f1;
        const float y2 = (float)acc2[i][j][qe] * f2;
        const float h = (y1 / (1.0f + expf(-y1))) * y2;   // silu(y1)*y2
        hr[j * 16] = h;
        lmax = fmaxf(lmax, fabsf(h));
      }
      // reduce across the 16 lanes sharing this row (lane>>4 fixed)
#pragma unroll
      for (int mk = 8; mk >= 1; mk >>= 1)
        lmax = fmaxf(lmax, __shfl_xor(lmax, mk, 64));
      if ((lane & 15) == 0)
        atomicMax((unsigned int*)(hmax + grow), __float_as_uint(lmax));
    }
  }
}

// ---------------- down GEMM (int8, pipelined): Out = Q2 * W3^T ----------------
#define DN_SLOT 24576   // A 16KB + B 8KB

__launch_bounds__(512, 2)
__global__ void gemm_down(const unsigned char* __restrict__ Aq,   // [Mc][K] i8
                          const unsigned char* __restrict__ Wq,   // [N][K] i8 ternary
                          const float* __restrict__ arow,
                          const double* __restrict__ wsum,
                          float* __restrict__ Out,                // [Mc][N] fp32
                          const int N, const int K,
                          const int MBb, const int NBb) {
  __shared__ char lds[3 * DN_SLOT];   // 72 KiB

  const int tid = threadIdx.x;
  const int lane = tid & 63;
  const int wid = tid >> 6;
  const int wm = wid >> 1;
  const int wn = wid & 1;

  const int total = MBb * NBb;
  int swz = blockIdx.x;
  if ((total & 7) == 0) swz = (swz & 7) * (total >> 3) + (swz >> 3);
  const int nb = swz % NBb;
  const int mb = swz / NBb;
  const int m0 = mb * 256;
  const int n0 = nb * 128;

  const unsigned char* Ab = Aq + (size_t)m0 * K;
  const unsigned char* Bb = Wq + (size_t)n0 * K;

  auto stage = [&](int kt, int s) {
    const int k0 = kt * BKP;
    char* base = lds + s * DN_SLOT;
#pragma unroll
    for (int is = 0; is < 2; ++is) {
      const int p = is * 8192 + wid * 1024 + lane * 16;
      const int r = p >> 6;
      const int c = ((p >> 4) & 3) ^ ((r >> 1) & 3);
      gload_lds16(Ab + (size_t)r * K + k0 + c * 16, base + is * 8192 + wid * 1024);
    }
    {
      const int p = wid * 1024 + lane * 16;
      const int r = p >> 6;
      const int c = ((p >> 4) & 3) ^ ((r >> 1) & 3);
      gload_lds16(Bb + (size_t)r * K + k0 + c * 16, base + 16384 + wid * 1024);
    }
  };

  const int c16 = lane >> 4;
  int offA[4], offB[4];
#pragma unroll
  for (int i = 0; i < 4; ++i) {
    const int row = wm * 64 + i * 16 + (lane & 15);
    offA[i] = row * 64 + ((c16 ^ ((row >> 1) & 3)) << 4);
  }
#pragma unroll
  for (int j = 0; j < 4; ++j) {
    const int n = wn * 64 + j * 16 + (lane & 15);
    offB[j] = 16384 + n * 64 + ((c16 ^ ((n >> 1) & 3)) << 4);
  }

  i32x4 acc[4][4] = {};

  const int NT = K / BKP;
  stage(0, 0);
  stage(1, 1);
  PIPE_BARRIER(3)                    // 6 issued; tile 0 (3) landed

  int s = 0, s2 = 2;
  for (int t = 0; t < NT; ++t) {
    if (t + 2 < NT) stage(t + 2, s2);
    const char* sb = lds + s * DN_SLOT;
    i32x4 af[4], bf[4];
#pragma unroll
    for (int i = 0; i < 4; ++i) af[i] = *(const i32x4*)(sb + offA[i]);
#pragma unroll
    for (int j = 0; j < 4; ++j) bf[j] = *(const i32x4*)(sb + offB[j]);
    __builtin_amdgcn_s_setprio(1);
#pragma unroll
    for (int j = 0; j < 4; ++j)
#pragma unroll
      for (int i = 0; i < 4; ++i)
        acc[i][j] = __builtin_amdgcn_mfma_i32_16x16x64_i8(af[i], bf[j], acc[i][j], 0, 0, 0);
    __builtin_amdgcn_s_setprio(0);
    if (t + 2 < NT) {
      PIPE_BARRIER(3)
    } else if (t + 1 < NT) {
      PIPE_BARRIER(0)
    }
    s = (s == 2) ? 0 : s + 1;
    s2 = (s2 == 2) ? 0 : s2 + 1;
  }

  const double inv_n = 1.0 / 11534336.0;
  const float sw3 = (float)fmax(wsum[2] * inv_n, (double)EPSQ);
#pragma unroll
  for (int i = 0; i < 4; ++i) {
    const int rb = m0 + wm * 64 + i * 16 + (lane >> 4) * 4;
#pragma unroll
    for (int qe = 0; qe < 4; ++qe) {
      const int grow = rb + qe;
      const float f = arow[grow] * sw3;
      float* orow = Out + (size_t)grow * N + n0 + wn * 64 + (lane & 15);
#pragma unroll
      for (int j = 0; j < 4; ++j) {
        orow[j * 16] = (float)acc[i][j][qe] * f;
      }
    }
  }
}

extern "C" void kernel_launch(void* const* d_in, const int* in_sizes, int n_in,
                              void* d_out, int out_size, void* d_ws, size_t ws_size,
                              hipStream_t stream) {
  (void)n_in; (void)out_size;
  const float* x  = (const float*)d_in[0];
  const float* w1 = (const float*)d_in[1];
  const float* w2 = (const float*)d_in[2];
  const float* w3 = (const float*)d_in[3];
  float* out = (float*)d_out;

  const int D = 2048, H = 5632;
  const int M = in_sizes[0] / D;             // 8192
  const long long NW = (long long)H * D;     // 11534336

  auto al = [](size_t v) { return (v + 255) & ~(size_t)255; };

  // fixed region: wsum + int8 quantized weights (34.6 MB)
  size_t off = 0;
  const size_t o_wsum = off; off += al(3 * sizeof(double));
  const size_t o_w1q  = off; off += al((size_t)NW);
  const size_t o_w2q  = off; off += al((size_t)NW);
  const size_t o_w3q  = off; off += al((size_t)NW);
  const size_t fixed = off;

  // adaptive chunk size: largest Mc (multiple of 256, power-of-2 fraction of M)
  int Mc = 256;
  for (int cand = M; cand >= 256; cand >>= 1) {
    size_t need = fixed
                + al((size_t)cand * 4)          // arow1
                + al((size_t)cand * 4)          // arow2 / hmax
                + al((size_t)cand * D)          // qx i8
                + al((size_t)cand * H * 4)      // hbuf fp32
                + al((size_t)cand * H);         // qh i8
    if (need <= ws_size) { Mc = cand; break; }
  }

  size_t coff = fixed;
  const size_t o_arow1 = coff; coff += al((size_t)Mc * 4);
  const size_t o_arow2 = coff; coff += al((size_t)Mc * 4);
  const size_t o_qx    = coff; coff += al((size_t)Mc * D);
  const size_t o_hbuf  = coff; coff += al((size_t)Mc * H * 4);
  const size_t o_qh    = coff; coff += al((size_t)Mc * H);

  char* ws = (char*)d_ws;
  double* wsum        = (double*)(ws + o_wsum);
  unsigned char* w1q  = (unsigned char*)(ws + o_w1q);
  unsigned char* w2q  = (unsigned char*)(ws + o_w2q);
  unsigned char* w3q  = (unsigned char*)(ws + o_w3q);
  float* arow1        = (float*)(ws + o_arow1);
  float* arow2        = (float*)(ws + o_arow2);
  unsigned char* qx   = (unsigned char*)(ws + o_qx);
  float* hbuf         = (float*)(ws + o_hbuf);
  unsigned char* qh   = (unsigned char*)(ws + o_qh);

  hipMemsetAsync(wsum, 0, 3 * sizeof(double), stream);

  const int n4w = (int)(NW / 4);                 // 2883584
  wabs3_kernel<<<dim3(1024, 3), 256, 0, stream>>>(w1, w2, w3, n4w, wsum);

  const double inv_n = 1.0 / (double)NW;
  wquant3_kernel<<<dim3(n4w / 256, 3), 256, 0, stream>>>(
      w1, w2, w3, n4w, wsum, inv_n,
      (unsigned int*)w1q, (unsigned int*)w2q, (unsigned int*)w3q);

  const int NBgu = H / 128;                      // 44
  const int NBdn = D / 128;                      // 16
  for (int c = 0; c < M; c += Mc) {
    const int MBb = Mc / 256;
    aquant_kernel<<<Mc, 256, 0, stream>>>(x + (size_t)c * D, D, qx, arow1);
    hipMemsetAsync(arow2, 0, (size_t)Mc * 4, stream);   // zero raw |h| maxima
    gemm_gateup<<<MBb * NBgu, 512, 0, stream>>>(qx, w1q, w2q, arow1, wsum,
                                                hbuf, arow2, H, D, MBb, NBgu);
    aquant_pre_kernel<<<Mc, 256, 0, stream>>>(hbuf, H, qh, arow2);
    gemm_down<<<MBb * NBdn, 512, 0, stream>>>(qh, w3q, arow2, wsum,
                                              out + (size_t)c * D, D, H, MBb, NBdn);
  }
}